// Round 1
// baseline (274.316 us; speedup 1.0000x reference)
//
#include <hip/hip_runtime.h>

#define BATCH 8192
#define FEATS 4096

// ws layout: [0, 4096) doubles = column sums; then 4096 floats = per-feature scale

__global__ __launch_bounds__(256) void colsum_kernel(const float* __restrict__ in,
                                                     double* __restrict__ sums) {
    // grid.x = 4 column groups of 1024 cols; grid.y = row chunks
    const int colBase = blockIdx.x * 1024 + threadIdx.x * 4;
    const int rowsPerBlk = BATCH / gridDim.y;
    const int row0 = blockIdx.y * rowsPerBlk;
    const float4* p = (const float4*)in + (size_t)row0 * (FEATS / 4) + (colBase >> 2);
    double a0 = 0.0, a1 = 0.0, a2 = 0.0, a3 = 0.0;
    for (int r = 0; r < rowsPerBlk; ++r) {
        float4 v = p[(size_t)r * (FEATS / 4)];
        a0 += (double)v.x; a1 += (double)v.y; a2 += (double)v.z; a3 += (double)v.w;
    }
    atomicAdd(&sums[colBase + 0], a0);
    atomicAdd(&sums[colBase + 1], a1);
    atomicAdd(&sums[colBase + 2], a2);
    atomicAdd(&sums[colBase + 3], a3);
}

__global__ __launch_bounds__(1024) void config_kernel(const double* __restrict__ sums,
                                                      const float* __restrict__ noise,
                                                      float* __restrict__ scale) {
    __shared__ double s_mean[FEATS];
    __shared__ double s_red[1024];
    __shared__ unsigned s_hist[FEATS + 1];
    const int tid = threadIdx.x;

    double lmin = 1e300, lmax = -1e300;
    for (int k = 0; k < 4; ++k) {
        int c = tid + k * 1024;
        double m = sums[c] * (1.0 / (double)BATCH);  // /8192: exact pow2 scale in fp64
        s_mean[c] = m;
        lmin = fmin(lmin, m);
        lmax = fmax(lmax, m);
    }
    // block min reduction
    s_red[tid] = lmin; __syncthreads();
    for (int s = 512; s > 0; s >>= 1) {
        if (tid < s) s_red[tid] = fmin(s_red[tid], s_red[tid + s]);
        __syncthreads();
    }
    const double xmin = s_red[0]; __syncthreads();
    // block max reduction
    s_red[tid] = lmax; __syncthreads();
    for (int s = 512; s > 0; s >>= 1) {
        if (tid < s) s_red[tid] = fmax(s_red[tid], s_red[tid + s]);
        __syncthreads();
    }
    const double xmax = s_red[0]; __syncthreads();

    for (int i = tid; i < FEATS + 1; i += 1024) s_hist[i] = 0;
    __syncthreads();

    int binr[4];
    const double denom = xmax - xmin;
    for (int k = 0; k < 4; ++k) {
        int c = tid + k * 1024;
        // match numpy op order exactly: F*(x - xmin) then divide, truncate-to-int
        double b = ((double)FEATS * (s_mean[c] - xmin)) / denom;
        int bi = (int)b;  // truncation toward zero, b >= 0
        binr[k] = bi;
        atomicAdd(&s_hist[bi], 1u);
    }
    __syncthreads();

    for (int k = 0; k < 4; ++k) {
        int c = tid + k * 1024;
        unsigned cnt = s_hist[binr[k]];
        double dr = (cnt == 1u) ? 0.1 : pow(0.1, 1.0 / (0.6 * (double)cnt));
        double sg = sqrt(dr / (1.0 - dr));
        scale[c] = (float)(1.0 + sg * (double)noise[c]);
    }
}

__global__ __launch_bounds__(256) void scale_kernel(const float4* __restrict__ in,
                                                    const float4* __restrict__ scale,
                                                    float4* __restrict__ out, int n4) {
    int idx = blockIdx.x * 256 + threadIdx.x;
    int stride = gridDim.x * 256;
    for (int i = idx; i < n4; i += stride) {
        float4 v = in[i];
        float4 s = scale[i & (FEATS / 4 - 1)];  // 1024 float4 per row
        v.x *= s.x; v.y *= s.y; v.z *= s.z; v.w *= s.w;
        out[i] = v;
    }
}

extern "C" void kernel_launch(void* const* d_in, const int* in_sizes, int n_in,
                              void* d_out, int out_size, void* d_ws, size_t ws_size,
                              hipStream_t stream) {
    const float* in = (const float*)d_in[0];
    const float* noise = (const float*)d_in[1];
    float* out = (float*)d_out;
    double* sums = (double*)d_ws;
    float* scale = (float*)(sums + FEATS);

    // ws is poisoned 0xAA before every launch — zero the accumulator region
    hipMemsetAsync(d_ws, 0, FEATS * sizeof(double), stream);

    dim3 g1(4, 128);
    colsum_kernel<<<g1, 256, 0, stream>>>(in, sums);
    config_kernel<<<1, 1024, 0, stream>>>(sums, noise, scale);
    scale_kernel<<<2048, 256, 0, stream>>>((const float4*)in, (const float4*)scale,
                                           (float4*)out, BATCH * FEATS / 4);
}

// Round 2
// 260.004 us; speedup vs baseline: 1.0550x; 1.0550x over previous
//
#include <hip/hip_runtime.h>

#define BATCH 8192
#define FEATS 4096
#define CHUNKS 128                 // row chunks for partial sums
#define ROWS_PER_CHUNK (BATCH / CHUNKS)   // 64

// ws layout: [0, CHUNKS*FEATS) doubles = partial column sums (4 MB)
//            then FEATS doubles = means (32 KB)
//            then FEATS floats  = per-feature scale (16 KB)

__global__ __launch_bounds__(256) void colsum_part(const float* __restrict__ in,
                                                   double* __restrict__ partials) {
    // grid.x = 4 column groups of 1024 cols; grid.y = CHUNKS row chunks
    const int colBase = blockIdx.x * 1024 + threadIdx.x * 4;
    const int row0 = blockIdx.y * ROWS_PER_CHUNK;
    const float4* p = (const float4*)in + (size_t)row0 * (FEATS / 4) + (colBase >> 2);
    double a0 = 0.0, a1 = 0.0, a2 = 0.0, a3 = 0.0;
#pragma unroll 8
    for (int r = 0; r < ROWS_PER_CHUNK; ++r) {
        float4 v = p[(size_t)r * (FEATS / 4)];
        a0 += (double)v.x; a1 += (double)v.y; a2 += (double)v.z; a3 += (double)v.w;
    }
    double* dst = partials + (size_t)blockIdx.y * FEATS + colBase;
    dst[0] = a0; dst[1] = a1; dst[2] = a2; dst[3] = a3;
}

__global__ __launch_bounds__(256) void reduce_mean(const double* __restrict__ partials,
                                                   double* __restrict__ means) {
    const int c = blockIdx.x * 256 + threadIdx.x;
    double s = 0.0;
#pragma unroll 8
    for (int k = 0; k < CHUNKS; ++k) s += partials[(size_t)k * FEATS + c];
    means[c] = s * (1.0 / (double)BATCH);  // /8192 exact pow2 scale
}

__global__ __launch_bounds__(1024) void config_kernel(const double* __restrict__ means,
                                                      const float* __restrict__ noise,
                                                      float* __restrict__ scale) {
    __shared__ double s_mean[FEATS];
    __shared__ double s_red[1024];
    __shared__ unsigned s_hist[FEATS + 1];
    const int tid = threadIdx.x;

    double lmin = 1e300, lmax = -1e300;
#pragma unroll
    for (int k = 0; k < 4; ++k) {
        int c = tid + k * 1024;
        double m = means[c];
        s_mean[c] = m;
        lmin = fmin(lmin, m);
        lmax = fmax(lmax, m);
    }
    s_red[tid] = lmin; __syncthreads();
    for (int s = 512; s > 0; s >>= 1) {
        if (tid < s) s_red[tid] = fmin(s_red[tid], s_red[tid + s]);
        __syncthreads();
    }
    const double xmin = s_red[0]; __syncthreads();
    s_red[tid] = lmax; __syncthreads();
    for (int s = 512; s > 0; s >>= 1) {
        if (tid < s) s_red[tid] = fmax(s_red[tid], s_red[tid + s]);
        __syncthreads();
    }
    const double xmax = s_red[0]; __syncthreads();

    for (int i = tid; i < FEATS + 1; i += 1024) s_hist[i] = 0;
    __syncthreads();

    int binr[4];
    const double denom = xmax - xmin;
#pragma unroll
    for (int k = 0; k < 4; ++k) {
        int c = tid + k * 1024;
        // match numpy op order: F*(x - xmin) then divide, truncate toward zero
        double b = ((double)FEATS * (s_mean[c] - xmin)) / denom;
        int bi = (int)b;
        binr[k] = bi;
        atomicAdd(&s_hist[bi], 1u);
    }
    __syncthreads();

    const double K = -2.302585092994045684017991454684364208;  // ln(0.1)
#pragma unroll
    for (int k = 0; k < 4; ++k) {
        int c = tid + k * 1024;
        unsigned cnt = s_hist[binr[k]];
        double dr = (cnt == 1u) ? 0.1 : exp(K / (0.6 * (double)cnt));
        double sg = sqrt(dr / (1.0 - dr));
        scale[c] = (float)(1.0 + sg * (double)noise[c]);
    }
}

__global__ __launch_bounds__(256) void scale_kernel(const float4* __restrict__ in,
                                                    const float4* __restrict__ scale,
                                                    float4* __restrict__ out) {
    const int i = blockIdx.x * 256 + threadIdx.x;
    float4 v = in[i];
    float4 s = scale[i & (FEATS / 4 - 1)];  // 1024 float4 per row
    v.x *= s.x; v.y *= s.y; v.z *= s.z; v.w *= s.w;
    out[i] = v;
}

extern "C" void kernel_launch(void* const* d_in, const int* in_sizes, int n_in,
                              void* d_out, int out_size, void* d_ws, size_t ws_size,
                              hipStream_t stream) {
    const float* in = (const float*)d_in[0];
    const float* noise = (const float*)d_in[1];
    float* out = (float*)d_out;
    double* partials = (double*)d_ws;
    double* means = partials + (size_t)CHUNKS * FEATS;
    float* scale = (float*)(means + FEATS);

    dim3 g1(4, CHUNKS);
    colsum_part<<<g1, 256, 0, stream>>>(in, partials);
    reduce_mean<<<FEATS / 256, 256, 0, stream>>>(partials, means);
    config_kernel<<<1, 1024, 0, stream>>>(means, noise, scale);
    scale_kernel<<<BATCH * FEATS / 4 / 256, 256, 0, stream>>>(
        (const float4*)in, (const float4*)scale, (float4*)out);
}